// Round 1
// 331.570 us; speedup vs baseline: 1.0226x; 1.0226x over previous
//
#include <hip/hip_runtime.h>

#define BB 4
#define CC 32
#define HH 512
#define WW 512
#define PLANE ((size_t)HH * WW)
#define NPIX ((size_t)BB * HH * WW)

// ---------------------------------------------------------------------------
// Kernel A: off_x/off_y = conv3x3(x, w_off[0:2]) + b_off[0:2].
// Thread: 4 w-px (float4) x 1 h-row. Block: 512w x 2 rows. Grid: 1024 blocks
// (4 waves/SIMD vs previous 2 — the kernel was latency-bound at 20% occupancy)
// with explicit 2-channel software pipeline: loads for ci+1/ci+2 are issued
// before the FMAs for ci, so each wave keeps a full channel of loads in
// flight. XCD-band swizzle: each XCD owns 256 contiguous rows of one batch.
// ---------------------------------------------------------------------------
__global__ __launch_bounds__(256) void conv_off_kernel(
    const float* __restrict__ x, const float* __restrict__ w_off,
    const float* __restrict__ b_off, float* __restrict__ off) {
  const int nb = gridDim.x;                       // 1024
  const int i  = blockIdx.x;
  const int j  = (i & 7) * (nb >> 3) + (i >> 3);  // XCD band swizzle
  const int b    = j >> 8;                        // 256 row-pairs per batch
  const int row0 = (j & 255) << 1;                // 2 rows per block

  const int t  = threadIdx.x;
  const int w4 = (t & 127) << 2;                  // 0..508
  const int h  = row0 + (t >> 7);                 // this thread: row h

  float4 a0v, a1v;                                // acc[out_ch] for 4 px
  a0v.x = a0v.y = a0v.z = a0v.w = b_off[0];
  a1v.x = a1v.y = a1v.z = a1v.w = b_off[1];

  const float* xb = x + (size_t)b * CC * PLANE + (size_t)h * WW + w4;

  float4 mA[3], mB[3];                            // rows h-1..h+1, double-buffered
  float vlA[3], vrA[3], vlB[3], vrB[3];

  auto load_ch = [&](int ci, float4* m, float* vl, float* vr) {
#pragma unroll
    for (int r = 0; r < 3; ++r) {
      const int hy = h - 1 + r;
      if (hy >= 0 && hy < HH) {
        const float* q = xb + (size_t)ci * PLANE + (ptrdiff_t)(r - 1) * WW;
        m[r] = *(const float4*)q;
        vl[r] = (w4 > 0) ? q[-1] : 0.f;
        vr[r] = (w4 < WW - 4) ? q[4] : 0.f;
      } else {
        m[r].x = m[r].y = m[r].z = m[r].w = 0.f;
        vl[r] = vr[r] = 0.f;
      }
    }
  };

  auto compute_ch = [&](int ci, const float4* m, const float* vl, const float* vr) {
    const float* wp0 = w_off + ci * 9;          // co=0: [ci][kh][kw]
    const float* wp1 = w_off + 288 + ci * 9;    // co=1
#pragma unroll
    for (int kh = 0; kh < 3; ++kh) {
      const float a0 = wp0[kh * 3 + 0], a1 = wp0[kh * 3 + 1], a2 = wp0[kh * 3 + 2];
      const float c0 = wp1[kh * 3 + 0], c1 = wp1[kh * 3 + 1], c2 = wp1[kh * 3 + 2];
      a0v.x += vl[kh] * a0 + m[kh].x * a1 + m[kh].y * a2;
      a0v.y += m[kh].x * a0 + m[kh].y * a1 + m[kh].z * a2;
      a0v.z += m[kh].y * a0 + m[kh].z * a1 + m[kh].w * a2;
      a0v.w += m[kh].z * a0 + m[kh].w * a1 + vr[kh] * a2;
      a1v.x += vl[kh] * c0 + m[kh].x * c1 + m[kh].y * c2;
      a1v.y += m[kh].x * c0 + m[kh].y * c1 + m[kh].z * c2;
      a1v.z += m[kh].y * c0 + m[kh].z * c1 + m[kh].w * c2;
      a1v.w += m[kh].z * c0 + m[kh].w * c1 + vr[kh] * c2;
    }
  };

  // 2-deep software pipeline over channels: loads for the next channel are
  // issued before the FMAs of the current one.
  load_ch(0, mA, vlA, vrA);
  for (int ci = 0; ci < CC - 2; ci += 2) {
    load_ch(ci + 1, mB, vlB, vrB);
    compute_ch(ci, mA, vlA, vrA);
    load_ch(ci + 2, mA, vlA, vrA);
    compute_ch(ci + 1, mB, vlB, vrB);
  }
  load_ch(CC - 1, mB, vlB, vrB);
  compute_ch(CC - 2, mA, vlA, vrA);
  compute_ch(CC - 1, mB, vlB, vrB);

  const size_t idx = ((size_t)b * HH + h) * WW + w4;
  *(float4*)(off + idx) = a0v;                 // off_x row h
  *(float4*)(off + NPIX + idx) = a1v;          // off_y row h
}

// ---------------------------------------------------------------------------
// Kernel B: bilinear zero-padded sample of 32 channels at (w+offx, h+offy).
// One thread per pixel; same XCD-band swizzle so each XCD gathers from a
// contiguous 256-row band (L2-resident per channel) and reads `off` written
// by the same XCD's L2. NT stores keep write-once output out of L2.
// ---------------------------------------------------------------------------
__global__ __launch_bounds__(256) void sample_kernel(
    const float* __restrict__ x, const float* __restrict__ off,
    float* __restrict__ out) {
  const int nb = gridDim.x;                       // 4096
  const int i  = blockIdx.x;
  const int j  = (i & 7) * (nb >> 3) + (i >> 3);  // XCD band swizzle
  const size_t tid = (size_t)j * 256 + threadIdx.x;

  const int w = (int)(tid & (WW - 1));
  const int h = (int)((tid >> 9) & (HH - 1));
  const int b = (int)(tid >> 18);

  const float ix = (float)w + off[tid];
  const float iy = (float)h + off[NPIX + tid];

  const float x0f = floorf(ix);
  const float y0f = floorf(iy);

  const float wx1 = ix - x0f;
  const float wx0 = 1.f - wx1;
  const float wy1 = iy - y0f;
  const float wy0 = 1.f - wy1;

  const bool vx0 = (x0f >= 0.f) && (x0f <= (float)(WW - 1));
  const bool vx1 = (x0f + 1.f >= 0.f) && (x0f + 1.f <= (float)(WW - 1));
  const bool vy0 = (y0f >= 0.f) && (y0f <= (float)(HH - 1));
  const bool vy1 = (y0f + 1.f >= 0.f) && (y0f + 1.f <= (float)(HH - 1));

  const int xi0 = (int)fminf(fmaxf(x0f, 0.f), (float)(WW - 1));
  const int xi1 = (int)fminf(fmaxf(x0f + 1.f, 0.f), (float)(WW - 1));
  const int yi0 = (int)fminf(fmaxf(y0f, 0.f), (float)(HH - 1));
  const int yi1 = (int)fminf(fmaxf(y0f + 1.f, 0.f), (float)(HH - 1));

  const float w00 = wy0 * wx0 * ((vy0 && vx0) ? 1.f : 0.f);
  const float w01 = wy0 * wx1 * ((vy0 && vx1) ? 1.f : 0.f);
  const float w10 = wy1 * wx0 * ((vy1 && vx0) ? 1.f : 0.f);
  const float w11 = wy1 * wx1 * ((vy1 && vx1) ? 1.f : 0.f);

  const int i00 = yi0 * WW + xi0;
  const int i01 = yi0 * WW + xi1;
  const int i10 = yi1 * WW + xi0;
  const int i11 = yi1 * WW + xi1;

  const float* xp = x + (size_t)b * CC * PLANE;
  float* ob = out + (size_t)b * CC * PLANE + (size_t)h * WW + w;

#pragma unroll 8
  for (int c = 0; c < CC; ++c) {
    const float v = w00 * xp[i00] + w01 * xp[i01] + w10 * xp[i10] + w11 * xp[i11];
    __builtin_nontemporal_store(v, ob);
    xp += PLANE;
    ob += PLANE;
  }
}

extern "C" void kernel_launch(void* const* d_in, const int* in_sizes, int n_in,
                              void* d_out, int out_size, void* d_ws, size_t ws_size,
                              hipStream_t stream) {
  const float* x     = (const float*)d_in[0];
  const float* w_off = (const float*)d_in[1];
  const float* b_off = (const float*)d_in[2];
  float* out = (float*)d_out;
  float* off = (float*)d_ws;  // 2 * B*H*W floats = 8 MB

  conv_off_kernel<<<1024, 256, 0, stream>>>(x, w_off, b_off, off);

  const int nblk = (int)(NPIX / 256);  // 4096
  sample_kernel<<<nblk, 256, 0, stream>>>(x, off, out);
}

// Round 2
// 303.632 us; speedup vs baseline: 1.1167x; 1.0920x over previous
//
#include <hip/hip_runtime.h>

#define BB 4
#define CC 32
#define HH 512
#define WW 512
#define PLANE ((size_t)HH * WW)
#define NPIX ((size_t)BB * HH * WW)

// ---------------------------------------------------------------------------
// Kernel A: off_x/off_y = conv3x3(x, w_off[0:2]) + b_off[0:2].
// Thread: 4 w-px (float4) x 1 h-row. Block: 512w x 2 rows. Grid: 1024 blocks.
// Edge pixels (w4-1, w4+4) come from neighbor LANES via shfl, not from
// scalar loads: the old per-row p[-1]/p[4] loads strided 16B/lane and
// touched 16 cache lines each — as expensive in L1 as the float4 loads
// themselves (2/3 of L1 traffic for 2/18 of the data). Only lanes 0/63 do
// one exec-masked 4B load per row for the wave-boundary column.
// 2-deep channel software pipeline; XCD band swizzle.
// ---------------------------------------------------------------------------
__global__ __launch_bounds__(256) void conv_off_kernel(
    const float* __restrict__ x, const float* __restrict__ w_off,
    const float* __restrict__ b_off, float* __restrict__ off) {
  const int nb = gridDim.x;                       // 1024
  const int i  = blockIdx.x;
  const int j  = (i & 7) * (nb >> 3) + (i >> 3);  // XCD band swizzle
  const int b    = j >> 8;                        // 256 row-pairs per batch
  const int row0 = (j & 255) << 1;

  const int t    = threadIdx.x;
  const int w4   = (t & 127) << 2;                // 0..508
  const int h    = row0 + (t >> 7);               // this thread: row h
  const int lane = t & 63;                        // wave covers one row span

  float4 a0v, a1v;                                // acc[out_ch] for 4 px
  a0v.x = a0v.y = a0v.z = a0v.w = b_off[0];
  a1v.x = a1v.y = a1v.z = a1v.w = b_off[1];

  const float* xb = x + (size_t)b * CC * PLANE + (size_t)h * WW + w4;

  float4 mA[3], mB[3];                            // rows h-1..h+1, dbuf
  float  eA[3], eB[3];                            // boundary-lane extras

  auto load_ch = [&](int ci, float4* m, float* e) {
#pragma unroll
    for (int r = 0; r < 3; ++r) {
      const int hy = h - 1 + r;
      const float* q = xb + (size_t)ci * PLANE + (ptrdiff_t)(r - 1) * WW;
      if (hy >= 0 && hy < HH) {
        m[r] = *(const float4*)q;
        // lane 0 needs q[-1] (left wave edge), lane 63 needs q[4] (right).
        const float* ea = (lane == 0) ? q - 1 : q + 4;
        const bool eok = (lane == 0) ? (w4 > 0)
                                     : (lane == 63 && w4 < WW - 4);
        e[r] = eok ? *ea : 0.f;
      } else {
        m[r].x = m[r].y = m[r].z = m[r].w = 0.f;
        e[r] = 0.f;
      }
    }
  };

  auto compute_ch = [&](int ci, const float4* m, const float* e) {
    const float* wp0 = w_off + ci * 9;          // co=0: [ci][kh][kw]
    const float* wp1 = w_off + 288 + ci * 9;    // co=1
#pragma unroll
    for (int kh = 0; kh < 3; ++kh) {
      float vl = __shfl_up(m[kh].w, 1);
      if (lane == 0) vl = e[kh];
      float vr = __shfl_down(m[kh].x, 1);
      if (lane == 63) vr = e[kh];
      const float a0 = wp0[kh * 3 + 0], a1 = wp0[kh * 3 + 1], a2 = wp0[kh * 3 + 2];
      const float c0 = wp1[kh * 3 + 0], c1 = wp1[kh * 3 + 1], c2 = wp1[kh * 3 + 2];
      a0v.x += vl * a0 + m[kh].x * a1 + m[kh].y * a2;
      a0v.y += m[kh].x * a0 + m[kh].y * a1 + m[kh].z * a2;
      a0v.z += m[kh].y * a0 + m[kh].z * a1 + m[kh].w * a2;
      a0v.w += m[kh].z * a0 + m[kh].w * a1 + vr * a2;
      a1v.x += vl * c0 + m[kh].x * c1 + m[kh].y * c2;
      a1v.y += m[kh].x * c0 + m[kh].y * c1 + m[kh].z * c2;
      a1v.z += m[kh].y * c0 + m[kh].z * c1 + m[kh].w * c2;
      a1v.w += m[kh].z * c0 + m[kh].w * c1 + vr * c2;
    }
  };

  // 2-deep software pipeline over channels.
  load_ch(0, mA, eA);
  for (int ci = 0; ci < CC - 2; ci += 2) {
    load_ch(ci + 1, mB, eB);
    compute_ch(ci, mA, eA);
    load_ch(ci + 2, mA, eA);
    compute_ch(ci + 1, mB, eB);
  }
  load_ch(CC - 1, mB, eB);
  compute_ch(CC - 2, mA, eA);
  compute_ch(CC - 1, mB, eB);

  const size_t idx = ((size_t)b * HH + h) * WW + w4;
  *(float4*)(off + idx) = a0v;                 // off_x row h
  *(float4*)(off + NPIX + idx) = a1v;          // off_y row h
}

// ---------------------------------------------------------------------------
// Kernel B: bilinear zero-padded sample of 32 channels at (w+offx, h+offy).
// One thread per pixel. Channel loop is split into two explicit 16-channel
// batches: issue all 64 gathers of a batch, then compute + NT-store — keeps
// ~64 loads in flight per wave (vs 32 with unroll-8), which is what a
// latency-bound gather needs. Same XCD-band swizzle; NT stores keep the
// write-once output out of L2.
// ---------------------------------------------------------------------------
__global__ __launch_bounds__(256) void sample_kernel(
    const float* __restrict__ x, const float* __restrict__ off,
    float* __restrict__ out) {
  const int nb = gridDim.x;                       // 4096
  const int i  = blockIdx.x;
  const int j  = (i & 7) * (nb >> 3) + (i >> 3);  // XCD band swizzle
  const size_t tid = (size_t)j * 256 + threadIdx.x;

  const int w = (int)(tid & (WW - 1));
  const int h = (int)((tid >> 9) & (HH - 1));
  const int b = (int)(tid >> 18);

  const float ix = (float)w + off[tid];
  const float iy = (float)h + off[NPIX + tid];

  const float x0f = floorf(ix);
  const float y0f = floorf(iy);

  const float wx1 = ix - x0f;
  const float wx0 = 1.f - wx1;
  const float wy1 = iy - y0f;
  const float wy0 = 1.f - wy1;

  const bool vx0 = (x0f >= 0.f) && (x0f <= (float)(WW - 1));
  const bool vx1 = (x0f + 1.f >= 0.f) && (x0f + 1.f <= (float)(WW - 1));
  const bool vy0 = (y0f >= 0.f) && (y0f <= (float)(HH - 1));
  const bool vy1 = (y0f + 1.f >= 0.f) && (y0f + 1.f <= (float)(HH - 1));

  const int xi0 = (int)fminf(fmaxf(x0f, 0.f), (float)(WW - 1));
  const int xi1 = (int)fminf(fmaxf(x0f + 1.f, 0.f), (float)(WW - 1));
  const int yi0 = (int)fminf(fmaxf(y0f, 0.f), (float)(HH - 1));
  const int yi1 = (int)fminf(fmaxf(y0f + 1.f, 0.f), (float)(HH - 1));

  const float w00 = wy0 * wx0 * ((vy0 && vx0) ? 1.f : 0.f);
  const float w01 = wy0 * wx1 * ((vy0 && vx1) ? 1.f : 0.f);
  const float w10 = wy1 * wx0 * ((vy1 && vx0) ? 1.f : 0.f);
  const float w11 = wy1 * wx1 * ((vy1 && vx1) ? 1.f : 0.f);

  const int i00 = yi0 * WW + xi0;
  const int i01 = yi0 * WW + xi1;
  const int i10 = yi1 * WW + xi0;
  const int i11 = yi1 * WW + xi1;

  const float* xp = x + (size_t)b * CC * PLANE;
  float* ob = out + (size_t)b * CC * PLANE + (size_t)h * WW + w;

#pragma unroll
  for (int half = 0; half < 2; ++half) {
    float v00[16], v01[16], v10[16], v11[16];
    const float* p = xp;
#pragma unroll
    for (int c = 0; c < 16; ++c) {      // issue 64 gathers back-to-back
      v00[c] = p[i00];
      v01[c] = p[i01];
      v10[c] = p[i10];
      v11[c] = p[i11];
      p += PLANE;
    }
    float* o = ob;
#pragma unroll
    for (int c = 0; c < 16; ++c) {      // consume + NT store
      const float v = w00 * v00[c] + w01 * v01[c] + w10 * v10[c] + w11 * v11[c];
      __builtin_nontemporal_store(v, o);
      o += PLANE;
    }
    xp += (size_t)16 * PLANE;
    ob += (size_t)16 * PLANE;
  }
}

extern "C" void kernel_launch(void* const* d_in, const int* in_sizes, int n_in,
                              void* d_out, int out_size, void* d_ws, size_t ws_size,
                              hipStream_t stream) {
  const float* x     = (const float*)d_in[0];
  const float* w_off = (const float*)d_in[1];
  const float* b_off = (const float*)d_in[2];
  float* out = (float*)d_out;
  float* off = (float*)d_ws;  // 2 * B*H*W floats = 8 MB

  conv_off_kernel<<<1024, 256, 0, stream>>>(x, w_off, b_off, off);

  const int nblk = (int)(NPIX / 256);  // 4096
  sample_kernel<<<nblk, 256, 0, stream>>>(x, off, out);
}

// Round 3
// 288.322 us; speedup vs baseline: 1.1760x; 1.0531x over previous
//
#include <hip/hip_runtime.h>

#define BB 4
#define CC 32
#define HH 512
#define WW 512
#define PLANE ((size_t)HH * WW)
#define NPIX ((size_t)BB * HH * WW)

// ---------------------------------------------------------------------------
// Kernel A: off_x/off_y = conv3x3(x, w_off[0:2]) + b_off[0:2].
// Thread: 4 w-px (float4) x 1 h-row. Block: 512w x 2 rows. Grid: 1024 blocks.
// Edge pixels come from neighbor lanes via shfl; only lanes 0/63 do one
// exec-masked 4B load per row. 2-deep channel pipeline; XCD band swizzle.
// ---------------------------------------------------------------------------
__global__ __launch_bounds__(256) void conv_off_kernel(
    const float* __restrict__ x, const float* __restrict__ w_off,
    const float* __restrict__ b_off, float* __restrict__ off) {
  const int nb = gridDim.x;                       // 1024
  const int i  = blockIdx.x;
  const int j  = (i & 7) * (nb >> 3) + (i >> 3);  // XCD band swizzle
  const int b    = j >> 8;                        // 256 row-pairs per batch
  const int row0 = (j & 255) << 1;

  const int t    = threadIdx.x;
  const int w4   = (t & 127) << 2;                // 0..508
  const int h    = row0 + (t >> 7);               // this thread: row h
  const int lane = t & 63;                        // wave covers one row span

  float4 a0v, a1v;                                // acc[out_ch] for 4 px
  a0v.x = a0v.y = a0v.z = a0v.w = b_off[0];
  a1v.x = a1v.y = a1v.z = a1v.w = b_off[1];

  const float* xb = x + (size_t)b * CC * PLANE + (size_t)h * WW + w4;

  float4 mA[3], mB[3];                            // rows h-1..h+1, dbuf
  float  eA[3], eB[3];                            // boundary-lane extras

  auto load_ch = [&](int ci, float4* m, float* e) {
#pragma unroll
    for (int r = 0; r < 3; ++r) {
      const int hy = h - 1 + r;
      const float* q = xb + (size_t)ci * PLANE + (ptrdiff_t)(r - 1) * WW;
      if (hy >= 0 && hy < HH) {
        m[r] = *(const float4*)q;
        // lane 0 needs q[-1] (left wave edge), lane 63 needs q[4] (right).
        const float* ea = (lane == 0) ? q - 1 : q + 4;
        const bool eok = (lane == 0) ? (w4 > 0)
                                     : (lane == 63 && w4 < WW - 4);
        e[r] = eok ? *ea : 0.f;
      } else {
        m[r].x = m[r].y = m[r].z = m[r].w = 0.f;
        e[r] = 0.f;
      }
    }
  };

  auto compute_ch = [&](int ci, const float4* m, const float* e) {
    const float* wp0 = w_off + ci * 9;          // co=0: [ci][kh][kw]
    const float* wp1 = w_off + 288 + ci * 9;    // co=1
#pragma unroll
    for (int kh = 0; kh < 3; ++kh) {
      float vl = __shfl_up(m[kh].w, 1);
      if (lane == 0) vl = e[kh];
      float vr = __shfl_down(m[kh].x, 1);
      if (lane == 63) vr = e[kh];
      const float a0 = wp0[kh * 3 + 0], a1 = wp0[kh * 3 + 1], a2 = wp0[kh * 3 + 2];
      const float c0 = wp1[kh * 3 + 0], c1 = wp1[kh * 3 + 1], c2 = wp1[kh * 3 + 2];
      a0v.x += vl * a0 + m[kh].x * a1 + m[kh].y * a2;
      a0v.y += m[kh].x * a0 + m[kh].y * a1 + m[kh].z * a2;
      a0v.z += m[kh].y * a0 + m[kh].z * a1 + m[kh].w * a2;
      a0v.w += m[kh].z * a0 + m[kh].w * a1 + vr * a2;
      a1v.x += vl * c0 + m[kh].x * c1 + m[kh].y * c2;
      a1v.y += m[kh].x * c0 + m[kh].y * c1 + m[kh].z * c2;
      a1v.z += m[kh].y * c0 + m[kh].z * c1 + m[kh].w * c2;
      a1v.w += m[kh].z * c0 + m[kh].w * c1 + vr * c2;
    }
  };

  // 2-deep software pipeline over channels.
  load_ch(0, mA, eA);
  for (int ci = 0; ci < CC - 2; ci += 2) {
    load_ch(ci + 1, mB, eB);
    compute_ch(ci, mA, eA);
    load_ch(ci + 2, mA, eA);
    compute_ch(ci + 1, mB, eB);
  }
  load_ch(CC - 1, mB, eB);
  compute_ch(CC - 2, mA, eA);
  compute_ch(CC - 1, mB, eB);

  const size_t idx = ((size_t)b * HH + h) * WW + w4;
  *(float4*)(off + idx) = a0v;                 // off_x row h
  *(float4*)(off + NPIX + idx) = a1v;          // off_y row h
}

// ---------------------------------------------------------------------------
// Kernel B: bilinear zero-padded sample of 32 channels at (w+offx, h+offy).
// One thread per pixel. The two x-corners (xi0, xi0+1) are adjacent words,
// so each (row, channel) needs ONE float2 gather instead of two scalar
// gathers: 128 -> 64 gather instructions per thread, halving per-wave
// address count and L1 line-touches. Boundary clamping is folded into
// per-thread pair weights (A0,A1,B0,B1) via selectors against xL =
// clamp(x0f, 0, W-2) — the channel loop is 2 loads + 4 FMAs + 1 NT store.
// 16-channel batches keep a deep in-flight load window. XCD band swizzle.
// ---------------------------------------------------------------------------
__global__ __launch_bounds__(256) void sample_kernel(
    const float* __restrict__ x, const float* __restrict__ off,
    float* __restrict__ out) {
  const int nb = gridDim.x;                       // 4096
  const int i  = blockIdx.x;
  const int j  = (i & 7) * (nb >> 3) + (i >> 3);  // XCD band swizzle
  const size_t tid = (size_t)j * 256 + threadIdx.x;

  const int w = (int)(tid & (WW - 1));
  const int h = (int)((tid >> 9) & (HH - 1));
  const int b = (int)(tid >> 18);

  const float ix = (float)w + off[tid];
  const float iy = (float)h + off[NPIX + tid];

  const float x0f = floorf(ix);
  const float y0f = floorf(iy);

  const float wx1 = ix - x0f;
  const float wx0 = 1.f - wx1;
  const float wy1 = iy - y0f;
  const float wy0 = 1.f - wy1;

  const bool vx0 = (x0f >= 0.f) && (x0f <= (float)(WW - 1));
  const bool vx1 = (x0f + 1.f >= 0.f) && (x0f + 1.f <= (float)(WW - 1));
  const bool vy0 = (y0f >= 0.f) && (y0f <= (float)(HH - 1));
  const bool vy1 = (y0f + 1.f >= 0.f) && (y0f + 1.f <= (float)(HH - 1));

  const int xi0 = (int)fminf(fmaxf(x0f, 0.f), (float)(WW - 1));
  const int xi1 = (int)fminf(fmaxf(x0f + 1.f, 0.f), (float)(WW - 1));
  const int yi0 = (int)fminf(fmaxf(y0f, 0.f), (float)(HH - 1));
  const int yi1 = (int)fminf(fmaxf(y0f + 1.f, 0.f), (float)(HH - 1));

  const float w00 = wy0 * wx0 * ((vy0 && vx0) ? 1.f : 0.f);
  const float w01 = wy0 * wx1 * ((vy0 && vx1) ? 1.f : 0.f);
  const float w10 = wy1 * wx0 * ((vy1 && vx0) ? 1.f : 0.f);
  const float w11 = wy1 * wx1 * ((vy1 && vx1) ? 1.f : 0.f);

  // float2-pair base column and fold of clamp into pair weights.
  const int xL = (int)fminf(fmaxf(x0f, 0.f), (float)(WW - 2));
  const int sel0 = (xi0 > xL) ? 1 : 0;   // corner0 sits in pair[1]?
  const int sel1 = (xi1 > xL) ? 1 : 0;   // corner1 sits in pair[1]?

  const float A0 = (sel0 ? 0.f : w00) + (sel1 ? 0.f : w01);  // row yi0, pair[0]
  const float A1 = (sel0 ? w00 : 0.f) + (sel1 ? w01 : 0.f);  // row yi0, pair[1]
  const float B0 = (sel0 ? 0.f : w10) + (sel1 ? 0.f : w11);  // row yi1, pair[0]
  const float B1 = (sel0 ? w10 : 0.f) + (sel1 ? w11 : 0.f);  // row yi1, pair[1]

  const int r0 = yi0 * WW + xL;
  const int r1 = yi1 * WW + xL;

  const float* xp = x + (size_t)b * CC * PLANE;
  float* ob = out + (size_t)b * CC * PLANE + (size_t)h * WW + w;

#pragma unroll
  for (int half = 0; half < 2; ++half) {
    float2 t0[16], t1[16];
    const float* p = xp;
#pragma unroll
    for (int c = 0; c < 16; ++c) {      // issue 32 float2 gathers back-to-back
      __builtin_memcpy(&t0[c], p + r0, 8);
      __builtin_memcpy(&t1[c], p + r1, 8);
      p += PLANE;
    }
    float* o = ob;
#pragma unroll
    for (int c = 0; c < 16; ++c) {      // consume + NT store
      const float v = t0[c].x * A0 + t0[c].y * A1 + t1[c].x * B0 + t1[c].y * B1;
      __builtin_nontemporal_store(v, o);
      o += PLANE;
    }
    xp += (size_t)16 * PLANE;
    ob += (size_t)16 * PLANE;
  }
}

extern "C" void kernel_launch(void* const* d_in, const int* in_sizes, int n_in,
                              void* d_out, int out_size, void* d_ws, size_t ws_size,
                              hipStream_t stream) {
  const float* x     = (const float*)d_in[0];
  const float* w_off = (const float*)d_in[1];
  const float* b_off = (const float*)d_in[2];
  float* out = (float*)d_out;
  float* off = (float*)d_ws;  // 2 * B*H*W floats = 8 MB

  conv_off_kernel<<<1024, 256, 0, stream>>>(x, w_off, b_off, off);

  const int nblk = (int)(NPIX / 256);  // 4096
  sample_kernel<<<nblk, 256, 0, stream>>>(x, off, out);
}